// Round 10
// baseline (105.930 us; speedup 1.0000x reference)
//
#include <hip/hip_runtime.h>
#include <hip/hip_bf16.h>
#include <math.h>

#define BB 65536
#define DD 256
#define KK 10
#define LOG_2PI 1.8378770664093453f

// ---------------------------------------------------------------------------
// Prep: grid = K blocks x 256 threads.
// Layout for VGPR-resident eighth-slices: wave c (c=0..7) owns global f4
// indices f = c*8 + j (j=0..7), i.e. dims [c*32, c*32+32). Slice c occupies
// dwords [c*640, (c+1)*640). Within a slice, f4 slot p = (j*K + k)*2 + half
// (half 0 = iv, 1 = -2*mu*iv). Main loads slice f4 #(i*64 + lane) into w[i]
// (i=0..2; slot p -> w[p>>6], lane p&63, broadcast via v_readlane with
// compile-time lane index). Also writes C[k].
// ---------------------------------------------------------------------------
__global__ __launch_bounds__(DD) void gmvae_prep(
    const float* __restrict__ mu_table,
    const float* __restrict__ logvar_table,
    float* __restrict__ tab,   // 2*K*D floats (20 KB)
    float* __restrict__ C)     // K floats
{
    const int k = blockIdx.x;
    const int d = threadIdx.x;
    const float lv = logvar_table[k * DD + d];
    const float m  = mu_table[k * DD + d];
    const float iv = expf(-lv);          // exact 1.0 when lv==0
    const float a  = m * iv;

    const int f    = d >> 2;             // global f4 index 0..63
    const int c    = f >> 3;             // wave slice 0..7
    const int j    = f & 7;              // f4 within slice
    const int comp = d & 3;
    const int base = c * 640 + ((j * KK + k) * 2) * 4 + comp;
    tab[base]     = iv;                  // half 0
    tab[base + 4] = -2.0f * a;           // half 1

    float p = fmaf(m, a, lv);            // mu^2*iv + lv
    __shared__ float red[4];
    #pragma unroll
    for (int off = 32; off > 0; off >>= 1)
        p += __shfl_down(p, off, 64);
    if ((threadIdx.x & 63) == 0)
        red[threadIdx.x >> 6] = p;
    __syncthreads();
    if (threadIdx.x == 0) {
        const float s2 = (red[0] + red[1]) + (red[2] + red[3]);
        C[k] = -0.5f * (s2 + 256.0f * LOG_2PI) + logf(0.1f);
    }
}

__device__ __forceinline__ float rl(float v, int lane) {
    return __int_as_float(__builtin_amdgcn_readlane(__float_as_int(v), lane));
}

// ---------------------------------------------------------------------------
// Main. Block = 512 threads = 8 waves, owns 64 rows. Wave c computes dims
// [c*32, c*32+32) for all 64 rows; lane = row. q read DIRECTLY from global
// per lane (no LDS staging, NO barriers in hot loop — R8/R9's stall was the
// barriered stage pipeline at 16 waves/CU). 8192 waves -> ~32 waves/CU:
// latency hidden by TLP. Coefficients VGPR-resident (w[0..2], 12 VGPRs),
// broadcast via v_readlane (compile-time lanes). One barrier total (combine).
// grid = B/64 = 1024 blocks x 512.
// ---------------------------------------------------------------------------
__global__ __launch_bounds__(512) void gmvae_main(
    const float* __restrict__ q_z,
    const float* __restrict__ tab,
    const float* __restrict__ C,
    float* __restrict__ out)
{
    __shared__ float comb[512 * 11];     // 22.5 KB, stride 11 (odd)

    const int t    = threadIdx.x;
    const int r    = t & 63;                                   // lane = row
    const int c    = __builtin_amdgcn_readfirstlane(t >> 6);   // wave id 0..7
    const int row0 = blockIdx.x * 64;

    // one-time coefficient slice load: slice f4 #(i*64 + lane) -> w[i]
    const float4* __restrict__ t4 =
        reinterpret_cast<const float4*>(tab) + c * 160;
    float4 w[3];
    w[0] = t4[r];
    w[1] = t4[64 + r];
    w[2] = t4[128 + (r & 31)];           // slots 128..159 (lanes 0..31)

    const float4* __restrict__ qp =
        reinterpret_cast<const float4*>(q_z) + (size_t)(row0 + r) * 64 + c * 8;

    float acc[KK];
    #pragma unroll
    for (int k = 0; k < KK; ++k) acc[k] = 0.f;

    float4 v[4];
    #pragma unroll
    for (int i = 0; i < 4; ++i) v[i] = qp[i];

    #pragma unroll
    for (int half = 0; half < 2; ++half) {
        float4 u[4];
        if (half == 0) {
            #pragma unroll
            for (int i = 0; i < 4; ++i) u[i] = qp[4 + i];   // prefetch
        }
        #pragma unroll
        for (int jj = 0; jj < 4; ++jj) {
            const int j = half * 4 + jj;
            const float4 q = v[jj];
            const float qx2 = q.x * q.x, qy2 = q.y * q.y;
            const float qz2 = q.z * q.z, qw2 = q.w * q.w;
            #pragma unroll
            for (int k = 0; k < KK; ++k) {
                const int p = (j * KK + k) * 2;      // iv f4 slot; na = p+1
                const int i = p >> 6;
                const int L = p & 63;
                const float4 wv = w[i];
                acc[k] = fmaf(qx2, rl(wv.x, L),     acc[k]);
                acc[k] = fmaf(q.x, rl(wv.x, L + 1), acc[k]);
                acc[k] = fmaf(qy2, rl(wv.y, L),     acc[k]);
                acc[k] = fmaf(q.y, rl(wv.y, L + 1), acc[k]);
                acc[k] = fmaf(qz2, rl(wv.z, L),     acc[k]);
                acc[k] = fmaf(q.z, rl(wv.z, L + 1), acc[k]);
                acc[k] = fmaf(qw2, rl(wv.w, L),     acc[k]);
                acc[k] = fmaf(q.w, rl(wv.w, L + 1), acc[k]);
            }
        }
        if (half == 0) {
            #pragma unroll
            for (int i = 0; i < 4; ++i) v[i] = u[i];
        }
    }

    // combine across the 8 waves (one barrier), then wave-0 epilogue
    #pragma unroll
    for (int k = 0; k < KK; ++k)
        comb[t * 11 + k] = acc[k];
    __syncthreads();

    if (t < 64) {
        float l[KK];
        #pragma unroll
        for (int k = 0; k < KK; ++k) {
            float s0 = 0.f, s1 = 0.f;
            #pragma unroll
            for (int cc = 0; cc < 4; ++cc) {
                s0 += comb[((2 * cc)     * 64 + r) * 11 + k];
                s1 += comb[((2 * cc + 1) * 64 + r) * 11 + k];
            }
            l[k] = fmaf(s0 + s1, -0.5f, C[k]);
        }

        float mx = l[0];
        #pragma unroll
        for (int k = 1; k < KK; ++k) mx = fmaxf(mx, l[k]);

        float e[KK];
        float sum = 0.f;
        #pragma unroll
        for (int k = 0; k < KK; ++k) { e[k] = __expf(l[k] - mx); sum += e[k]; }
        const float inv = 1.0f / sum;

        int idx = 0;
        float best = l[0];
        #pragma unroll
        for (int k = 1; k < KK; ++k)
            if (l[k] > best) { best = l[k]; idx = k; }

        const int row = row0 + r;
        float2* __restrict__ o1 =
            reinterpret_cast<float2*>(out) + (size_t)row * 5;
        float2* __restrict__ o2 =
            reinterpret_cast<float2*>(out + (size_t)BB * KK) + (size_t)row * 5;
        #pragma unroll
        for (int k = 0; k < 5; ++k)
            o1[k] = make_float2(l[2 * k], l[2 * k + 1]);
        #pragma unroll
        for (int k = 0; k < 5; ++k)
            o2[k] = make_float2(e[2 * k] * inv, e[2 * k + 1] * inv);
        out[(size_t)2 * BB * KK + row] = (float)idx;
    }
}

extern "C" void kernel_launch(void* const* d_in, const int* in_sizes, int n_in,
                              void* d_out, int out_size, void* d_ws, size_t ws_size,
                              hipStream_t stream) {
    const float* q_z    = (const float*)d_in[0];
    const float* mu     = (const float*)d_in[1];
    const float* logvar = (const float*)d_in[2];
    float* out = (float*)d_out;

    float* tab = (float*)d_ws;          // 5120 floats
    float* C   = tab + 5120;            // 10 floats

    gmvae_prep<<<KK, DD, 0, stream>>>(mu, logvar, tab, C);
    gmvae_main<<<BB / 64, 512, 0, stream>>>(q_z, tab, C, out);
}